// Round 7
// baseline (2001.783 us; speedup 1.0000x reference)
//
#include <hip/hip_runtime.h>

#define Bsz 256
#define Gn 100
#define GG 10000
#define IND 128
#define KD 32
#define NH 8
#define S_TOT 10000
#define CHUNK 2048               // Bsz*NH (elements per step)
#define NROWS_H 1280000          // 5000*256 rows per LSTM phase
#define NORMC 0.17677669529663687f
#define LOG2E 1.4426950408889634f
#define TWO_LOG2E 2.8853900817779268f

// ws layout (bytes): [ys f16 40,960,000][V f32 26,214,400][gx 81,920,000]
// comp f16 (20.48 MB) transiently occupies the ys region before lstm phase A.
// heads f32 (26.2 MB) reuses the gx region after lstm phase B.
#define V_OFF    40960000ull
#define GX_OFF   67174400ull
#define WS_MIN   149094400ull

// out layout (floats)
#define OUT_H 3276800
#define OUT_C 3278848

typedef _Float16 half2_t __attribute__((ext_vector_type(2)));
typedef _Float16 half4_t __attribute__((ext_vector_type(4)));

__global__ void k_wsfail(float* out, float v) { out[0] = v; }

// ---------------- kernel 1: Q/K projection + node compatibility (f16 out) ----------------
__global__ __launch_bounds__(256) void k_qk_comp(const float* __restrict__ X,
        const float* __restrict__ Wq, const float* __restrict__ Wk,
        _Float16* __restrict__ comp16)
{
    int h = blockIdx.x >> 8, b = blockIdx.x & 255;
    __shared__ float Qs[Gn * 33];
    __shared__ float Ks[Gn * 33];
    const float* Xb = X + (size_t)b * Gn * IND;
    const float* wq = Wq + h * IND * KD;
    const float* wk = Wk + h * IND * KD;
    int k = threadIdx.x & 31, ii = threadIdx.x >> 5;
    for (int i0 = 0; i0 < Gn; i0 += 8) {
        int i = i0 + ii;
        if (i < Gn) {
            float aq = 0.f, ak = 0.f;
            const float* xr = Xb + i * IND;
            #pragma unroll 8
            for (int c = 0; c < IND; ++c) {
                float x = xr[c];
                aq = fmaf(x, wq[c * KD + k], aq);
                ak = fmaf(x, wk[c * KD + k], ak);
            }
            Qs[i * 33 + k] = aq;
            Ks[i * 33 + k] = ak;
        }
    }
    __syncthreads();
    _Float16* cb = comp16 + (size_t)blockIdx.x * GG;
    for (int idx = threadIdx.x; idx < GG; idx += 256) {
        int i = idx / 100, j = idx - i * 100;
        float acc = 0.f;
        #pragma unroll
        for (int kk = 0; kk < KD; ++kk)
            acc = fmaf(Qs[i * 33 + kk], Ks[j * 33 + kk], acc);
        cb[idx] = (_Float16)(acc * NORMC);
    }
}

// ---------------- kernel 2: V projection ----------------
__global__ __launch_bounds__(256) void k_vproj(const float* __restrict__ X,
        const float* __restrict__ Wv, float* __restrict__ V)
{
    int h = blockIdx.x >> 8, b = blockIdx.x & 255;
    __shared__ float Xs[Gn * IND];
    const float4* X4 = (const float4*)(X + (size_t)b * Gn * IND);
    float4* Xs4 = (float4*)Xs;
    for (int i = threadIdx.x; i < Gn * IND / 4; i += 256) Xs4[i] = X4[i];
    __syncthreads();
    const float* wv = Wv + h * IND * KD;
    int k = threadIdx.x & 31, ii = threadIdx.x >> 5;
    float* vb = V + (size_t)blockIdx.x * (Gn * KD);
    for (int i0 = 0; i0 < Gn; i0 += 8) {
        int i = i0 + ii;
        if (i < Gn) {
            float a = 0.f;
            #pragma unroll 8
            for (int c = 0; c < IND; ++c)
                a = fmaf(Xs[i * IND + c], wv[c * KD + k], a);
            vb[i * KD + k] = a;
        }
    }
}

// -------- gx kernels: per (step,batch) row, per 16-lane, 2 gates --------
// gx value = -ks_q*(bih+bhh + Wc*cost + Wbc*bcost + sum_v Wih*x_v)  (NEGATED, prescaled)
// layout: gx[rid * 16 + lane16] as packed half2 (gate 2p, gate 2p+1), rid = t*256 + b

struct GxW {
    float wxa[8], wxb[8], ba, bb, wca, wcb, wbca, wbcb;
};

static __device__ __forceinline__ GxW gx_weights(int lane16,
        const float* Wih, const float* bih, const float* bhh)
{
    int u = lane16 & 7, p = lane16 >> 3;
    int qa = 2 * p, qb = 2 * p + 1;
    int ra = qa * 8 + u, rb = qb * 8 + u;
    float ksa = (qa == 2) ? TWO_LOG2E : LOG2E;
    float ksb = LOG2E;
    GxW w;
    #pragma unroll
    for (int v = 0; v < 8; ++v) {
        w.wxa[v] = -Wih[ra * 10 + v] * ksa;
        w.wxb[v] = -Wih[rb * 10 + v] * ksb;
    }
    w.ba = -(bih[ra] + bhh[ra]) * ksa;
    w.bb = -(bih[rb] + bhh[rb]) * ksb;
    w.wca  = -Wih[ra * 10 + 8] * ksa;
    w.wcb  = -Wih[rb * 10 + 8] * ksb;
    w.wbca = -Wih[ra * 10 + 9] * ksa;
    w.wbcb = -Wih[rb * 10 + 9] * ksb;
    return w;
}

__global__ __launch_bounds__(256) void k_gx_node(const _Float16* __restrict__ comp16,
        const float* __restrict__ cost, const float* __restrict__ bcost,
        const float* __restrict__ Wih, const float* __restrict__ bih,
        const float* __restrict__ bhh, unsigned* __restrict__ gx)
{
    int lane16 = threadIdx.x & 15, lr = threadIdx.x >> 4;
    GxW w = gx_weights(lane16, Wih, bih, bhh);
    for (int it = 0; it < 40; ++it) {
        int rid = it * 32768 + blockIdx.x * 16 + lr;
        if (rid >= NROWS_H) return;
        int b = rid & 255;
        int4 xr = *(const int4*)(comp16 + (size_t)rid * 8);
        half2_t x01 = __builtin_bit_cast(half2_t, xr.x);
        half2_t x23 = __builtin_bit_cast(half2_t, xr.y);
        half2_t x45 = __builtin_bit_cast(half2_t, xr.z);
        half2_t x67 = __builtin_bit_cast(half2_t, xr.w);
        float xv[8] = {(float)x01[0], (float)x01[1], (float)x23[0], (float)x23[1],
                       (float)x45[0], (float)x45[1], (float)x67[0], (float)x67[1]};
        float cv = cost[b], bv = bcost[b];
        float ga = fmaf(w.wca, cv, fmaf(w.wbca, bv, w.ba));
        float gb = fmaf(w.wcb, cv, fmaf(w.wbcb, bv, w.bb));
        #pragma unroll
        for (int v = 0; v < 8; ++v) {
            ga = fmaf(w.wxa[v], xv[v], ga);
            gb = fmaf(w.wxb[v], xv[v], gb);
        }
        half2_t o = {(_Float16)ga, (_Float16)gb};
        gx[(size_t)rid * 16 + lane16] = __builtin_bit_cast(unsigned, o);
    }
}

__global__ __launch_bounds__(256) void k_gx_pb(const float* __restrict__ pos,
        const float* __restrict__ best,
        const float* __restrict__ cost, const float* __restrict__ bcost,
        const float* __restrict__ Wih, const float* __restrict__ bih,
        const float* __restrict__ bhh, unsigned* __restrict__ gx)
{
    int lane16 = threadIdx.x & 15, lr = threadIdx.x >> 4;
    GxW w = gx_weights(lane16, Wih, bih, bhh);
    for (int it = 0; it < 40; ++it) {
        int rid = it * 32768 + blockIdx.x * 16 + lr;
        if (rid >= NROWS_H) return;
        int b = rid & 255;
        const float* src = (rid < 640000) ? (pos + (size_t)rid * 8)
                                          : (best + (size_t)(rid - 640000) * 8);
        float4 lo = ((const float4*)src)[0];
        float4 hi = ((const float4*)src)[1];
        float xv[8] = {lo.x, lo.y, lo.z, lo.w, hi.x, hi.y, hi.z, hi.w};
        float cv = cost[b], bv = bcost[b];
        float ga = fmaf(w.wca, cv, fmaf(w.wbca, bv, w.ba));
        float gb = fmaf(w.wcb, cv, fmaf(w.wbcb, bv, w.bb));
        #pragma unroll
        for (int v = 0; v < 8; ++v) {
            ga = fmaf(w.wxa[v], xv[v], ga);
            gb = fmaf(w.wxb[v], xv[v], gb);
        }
        half2_t o = {(_Float16)ga, (_Float16)gb};
        gx[(size_t)rid * 16 + lane16] = __builtin_bit_cast(unsigned, o);
    }
}

// ---------------- LSTM phase kernel: 5000 steps, gx-driven ----------------
// 64 blocks x 64 threads; lane = bw*16 + p*8 + u; p=0 gates {i,f}, p=1 {g,o}.

#define DPP(ctl, x) __builtin_amdgcn_update_dpp(0, (x), (ctl), 0xF, 0xF, true)

#define DPP_GATHER() \
    int hbi = __float_as_int(hcur); \
    int d1 = DPP(0xB1, hbi); \
    int d2 = DPP(0x4E, hbi); \
    int d3 = DPP(0x4E, d1); \
    int d7 = DPP(0x141, hbi); \
    int d6 = DPP(0x141, d1); \
    int d5 = DPP(0x141, d2); \
    int d4 = DPP(0x141, d3); \
    float hv0 = hcur; \
    float hv1 = __int_as_float(d1); \
    float hv2 = __int_as_float(d2); \
    float hv3 = __int_as_float(d3); \
    float hv4 = __int_as_float(d7); \
    float hv5 = __int_as_float(d6); \
    float hv6 = __int_as_float(d5); \
    float hv7 = __int_as_float(d4);

#define PH_BODY(SL, T, PF) do { \
    half2_t g2 = __builtin_bit_cast(half2_t, SL); \
    float na = (float)g2[0]; \
    float nb = (float)g2[1]; \
    if (PF) { const unsigned* gs = gx + (size_t)((T) + 8) * 4096; SL = gs[vo]; } \
    DPP_GATHER(); \
    na = fmaf(wha[0], hv0, na); nb = fmaf(whb[0], hv0, nb); \
    na = fmaf(wha[1], hv1, na); nb = fmaf(whb[1], hv1, nb); \
    na = fmaf(wha[2], hv2, na); nb = fmaf(whb[2], hv2, nb); \
    na = fmaf(wha[3], hv3, na); nb = fmaf(whb[3], hv3, nb); \
    na = fmaf(wha[4], hv4, na); nb = fmaf(whb[4], hv4, nb); \
    na = fmaf(wha[5], hv5, na); nb = fmaf(whb[5], hv5, nb); \
    na = fmaf(wha[6], hv6, na); nb = fmaf(whb[6], hv6, nb); \
    na = fmaf(wha[7], hv7, na); nb = fmaf(whb[7], hv7, nb); \
    float A = __builtin_amdgcn_rcpf(1.f + __builtin_amdgcn_exp2f(na)); \
    float B = __builtin_amdgcn_rcpf(1.f + __builtin_amdgcn_exp2f(nb)); \
    float rA = __int_as_float(DPP(0x128, __float_as_int(A))); \
    float rB = __int_as_float(DPP(0x128, __float_as_int(B))); \
    float si = pm ? rA : A; \
    float sf = pm ? rB : B; \
    float s2 = pm ? A : rA; \
    float so = pm ? B : rB; \
    ccur = fmaf(sf, ccur, si * fmaf(2.f, s2, -1.f)); \
    float tc = fmaf(2.f, __builtin_amdgcn_rcpf(1.f + __builtin_amdgcn_exp2f(ccur * -TWO_LOG2E)), -1.f); \
    hcur = so * tc; \
    { _Float16* yst = ysb + (size_t)(T) * 2048; \
      if (!pm) yst[b8 + u] = (_Float16)hcur; } \
} while (0)

__global__ __launch_bounds__(64, 1) void k_lstm_ph(
        const unsigned* __restrict__ gx, const float* __restrict__ hin,
        const float* __restrict__ cin, const float* __restrict__ Whh,
        _Float16* __restrict__ ysb, float* __restrict__ hout,
        float* __restrict__ cout)
{
    int lane = threadIdx.x;
    int u = lane & 7;
    int p = (lane >> 3) & 1;
    int bw = lane >> 4;
    int b = blockIdx.x * 4 + bw;
    int b8 = b * 8;
    bool pm = (p != 0);

    const int xm[8] = {0, 1, 2, 3, 7, 6, 5, 4};
    int qa = 2 * p, qb = 2 * p + 1;
    int ra = qa * 8 + u, rb = qb * 8 + u;
    float ksa = (qa == 2) ? TWO_LOG2E : LOG2E;
    float ksb = LOG2E;
    float wha[8], whb[8];
    #pragma unroll
    for (int j = 0; j < 8; ++j) {
        wha[j] = -Whh[ra * 8 + (u ^ xm[j])] * ksa;
        whb[j] = -Whh[rb * 8 + (u ^ xm[j])] * ksb;
    }
    float hcur = hin[b8 + u], ccur = cin[b8 + u];

    const unsigned vo = b * 16 + (lane & 15);   // dword index within a step row
    unsigned S0 = gx[(size_t)0 * 4096 + vo];
    unsigned S1 = gx[(size_t)1 * 4096 + vo];
    unsigned S2 = gx[(size_t)2 * 4096 + vo];
    unsigned S3 = gx[(size_t)3 * 4096 + vo];
    unsigned S4 = gx[(size_t)4 * 4096 + vo];
    unsigned S5 = gx[(size_t)5 * 4096 + vo];
    unsigned S6 = gx[(size_t)6 * 4096 + vo];
    unsigned S7 = gx[(size_t)7 * 4096 + vo];

    for (int t = 0; t < 4992; t += 8) {
        PH_BODY(S0, t + 0, 1);
        PH_BODY(S1, t + 1, 1);
        PH_BODY(S2, t + 2, 1);
        PH_BODY(S3, t + 3, 1);
        PH_BODY(S4, t + 4, 1);
        PH_BODY(S5, t + 5, 1);
        PH_BODY(S6, t + 6, 1);
        PH_BODY(S7, t + 7, 1);
    }
    PH_BODY(S0, 4992, 0);
    PH_BODY(S1, 4993, 0);
    PH_BODY(S2, 4994, 0);
    PH_BODY(S3, 4995, 0);
    PH_BODY(S4, 4996, 0);
    PH_BODY(S5, 4997, 0);
    PH_BODY(S6, 4998, 0);
    PH_BODY(S7, 4999, 0);

    if (!pm) {
        hout[b8 + u] = hcur;
        cout[b8 + u] = ccur;
    }
}

// ---------------- kernel 4: softmax rows + attn @ V (ys in f16) ----------------
__global__ __launch_bounds__(256) void k_softmax_av(const _Float16* __restrict__ ys,
        const float* __restrict__ V, float* __restrict__ heads)
{
    __shared__ float P[Gn * 101];
    __shared__ float Vs[Gn * 33];
    __shared__ float pm[256];
    __shared__ float rmaxs[Gn];
    __shared__ float rinvs[Gn];
    const _Float16* ysrc = ys + (size_t)blockIdx.x * GG;
    for (int it = 0; it < 10; ++it) {
        int base = (it * 256 + threadIdx.x) * 4;
        if (base < GG) {
            half4_t v4 = *(const half4_t*)(ysrc + base);
            int i = base / 100, j = base - i * 100;
            float* row = P + i * 101 + j;
            row[0] = (float)v4[0];
            row[1] = (float)v4[1];
            row[2] = (float)v4[2];
            row[3] = (float)v4[3];
        }
    }
    const float* vsrc = V + (size_t)blockIdx.x * (Gn * KD);
    for (int idx = threadIdx.x; idx < Gn * KD; idx += 256) {
        int i = idx >> 5, d = idx & 31;
        Vs[i * 33 + d] = vsrc[idx];
    }
    __syncthreads();
    int t = threadIdx.x;
    if (t < 200) {
        const float* row = P + (t >> 1) * 101 + (t & 1) * 50;
        float m = -1e30f;
        #pragma unroll 5
        for (int j = 0; j < 50; ++j) m = fmaxf(m, row[j]);
        pm[t] = m;
    }
    __syncthreads();
    if (t < Gn) rmaxs[t] = fmaxf(pm[2 * t], pm[2 * t + 1]);
    __syncthreads();
    if (t < 200) {
        float* row = P + (t >> 1) * 101 + (t & 1) * 50;
        float m = rmaxs[t >> 1];
        float ss = 0.f;
        #pragma unroll 5
        for (int j = 0; j < 50; ++j) {
            float e = __builtin_amdgcn_exp2f((row[j] - m) * LOG2E);
            row[j] = e; ss += e;
        }
        pm[t] = ss;
    }
    __syncthreads();
    if (t < Gn) rinvs[t] = __builtin_amdgcn_rcpf(pm[2 * t] + pm[2 * t + 1]);
    __syncthreads();
    int d = t & 31, ii = t >> 5;
    float* hb = heads + (size_t)blockIdx.x * (Gn * KD);
    for (int i0 = 0; i0 < Gn; i0 += 8) {
        int i = i0 + ii;
        if (i < Gn) {
            float acc = 0.f;
            #pragma unroll 4
            for (int j = 0; j < Gn; ++j)
                acc = fmaf(P[i * 101 + j], Vs[j * 33 + d], acc);
            hb[i * KD + d] = acc * rinvs[i];
        }
    }
}

// ---------------- kernel 5: output projection ----------------
__global__ __launch_bounds__(256) void k_outproj(const float* __restrict__ heads,
        const float* __restrict__ Wo, float* __restrict__ out)
{
    int b = blockIdx.x / 13, p = blockIdx.x % 13;
    int e = threadIdx.x & 127, half = threadIdx.x >> 7;
    int r0 = p * 8 + half * 4;
    float acc0 = 0.f, acc1 = 0.f, acc2 = 0.f, acc3 = 0.f;
    for (int h = 0; h < NH; ++h) {
        const float* hs = heads + (size_t)h * (256 * Gn * KD) + (size_t)b * (Gn * KD);
        const float* wsrc = Wo + h * (KD * IND);
        #pragma unroll 8
        for (int d = 0; d < KD; ++d) {
            float w = wsrc[d * IND + e];
            if (r0 + 3 < Gn) {
                acc0 = fmaf(hs[(r0 + 0) * KD + d], w, acc0);
                acc1 = fmaf(hs[(r0 + 1) * KD + d], w, acc1);
                acc2 = fmaf(hs[(r0 + 2) * KD + d], w, acc2);
                acc3 = fmaf(hs[(r0 + 3) * KD + d], w, acc3);
            } else {
                if (r0 + 0 < Gn) acc0 = fmaf(hs[(r0 + 0) * KD + d], w, acc0);
                if (r0 + 1 < Gn) acc1 = fmaf(hs[(r0 + 1) * KD + d], w, acc1);
                if (r0 + 2 < Gn) acc2 = fmaf(hs[(r0 + 2) * KD + d], w, acc2);
                if (r0 + 3 < Gn) acc3 = fmaf(hs[(r0 + 3) * KD + d], w, acc3);
            }
        }
    }
    if (r0 + 0 < Gn) out[((size_t)b * Gn + r0 + 0) * IND + e] = acc0;
    if (r0 + 1 < Gn) out[((size_t)b * Gn + r0 + 1) * IND + e] = acc1;
    if (r0 + 2 < Gn) out[((size_t)b * Gn + r0 + 2) * IND + e] = acc2;
    if (r0 + 3 < Gn) out[((size_t)b * Gn + r0 + 3) * IND + e] = acc3;
}

extern "C" void kernel_launch(void* const* d_in, const int* in_sizes, int n_in,
                              void* d_out, int out_size, void* d_ws, size_t ws_size,
                              hipStream_t stream) {
    const float* X     = (const float*)d_in[0];
    const float* pos   = (const float*)d_in[1];
    const float* best  = (const float*)d_in[2];
    const float* cost  = (const float*)d_in[3];
    const float* bcost = (const float*)d_in[4];
    const float* h0    = (const float*)d_in[5];
    const float* c0    = (const float*)d_in[6];
    const float* Wq    = (const float*)d_in[7];
    const float* Wk    = (const float*)d_in[8];
    const float* Wv    = (const float*)d_in[9];
    const float* Wo    = (const float*)d_in[10];
    const float* Wih   = (const float*)d_in[11];
    const float* Whh   = (const float*)d_in[12];
    const float* bih   = (const float*)d_in[13];
    const float* bhh   = (const float*)d_in[14];
    float* out = (float*)d_out;
    char* ws = (char*)d_ws;

    if (ws_size < WS_MIN) {
        k_wsfail<<<1, 1, 0, stream>>>(out, (float)ws_size);
        return;
    }

    _Float16* ys16   = (_Float16*)ws;                 // 41.0 MB (comp16 transient)
    _Float16* comp16 = (_Float16*)ws;
    float*    Vw     = (float*)(ws + V_OFF);          // 26.2 MB
    unsigned* gxw    = (unsigned*)(ws + GX_OFF);      // 81.9 MB
    float*    headsw = (float*)(ws + GX_OFF);         // reuses gx after LSTM

    k_qk_comp<<<1024, 256, 0, stream>>>(X, Wq, Wk, comp16);
    k_vproj<<<2048, 256, 0, stream>>>(X, Wv, Vw);
    k_gx_node<<<2048, 256, 0, stream>>>(comp16, cost, bcost, Wih, bih, bhh, gxw);
    k_lstm_ph<<<64, 64, 0, stream>>>(gxw, h0, c0, Whh, ys16,
                                     out + OUT_H, out + OUT_C);
    k_gx_pb<<<2048, 256, 0, stream>>>(pos, best, cost, bcost, Wih, bih, bhh, gxw);
    k_lstm_ph<<<64, 64, 0, stream>>>(gxw, out + OUT_H, out + OUT_C, Whh,
                                     ys16 + (size_t)5000 * CHUNK,
                                     out + OUT_H, out + OUT_C);
    k_softmax_av<<<2048, 256, 0, stream>>>(ys16, Vw, headsw);
    k_outproj<<<256 * 13, 256, 0, stream>>>(headsw, Wo, out);
}